// Round 11
// baseline (301.525 us; speedup 1.0000x reference)
//
#include <hip/hip_runtime.h>

// MultiHopGCN: x[N,128] f32, edge_index[2,E] i32, W1[128,64], b1[64], hw1[2],
//              W2[64,64], b2[64], hw2[2] -> out[N,64] f32
// Bucketed-CSC build fused with layer-1 GEMM; wave-per-node gather.
// bf16 intermediate features; nontemporal bucket stores/loads (bucket is
// write-once/read-streamed -> keep L2 for the randomly re-read feature rows).

#define TPB 256
#define CAP 40
#define OVF_CAP 65536

typedef int int4v __attribute__((ext_vector_type(4)));

// bf16 helpers (RNE)
__device__ __forceinline__ ushort f2b(float f) {
    union { float f; unsigned u; } v; v.f = f;
    unsigned r = v.u + 0x7FFFu + ((v.u >> 16) & 1u);
    return (ushort)(r >> 16);
}
__device__ __forceinline__ float b2f(ushort b) {
    union { unsigned u; float f; } v; v.u = ((unsigned)b) << 16;
    return v.f;
}
__device__ __forceinline__ float4 b4f(ushort4 b) {
    return make_float4(b2f(b.x), b2f(b.y), b2f(b.z), b2f(b.w));
}
__device__ __forceinline__ ushort4 f4b(float4 f) {
    ushort4 r; r.x = f2b(f.x); r.y = f2b(f.y); r.z = f2b(f.z); r.w = f2b(f.w);
    return r;
}

// ---- fused build + lin128 -------------------------------------------------
// Build blocks and GEMM blocks Bresenham-interleaved so both kinds co-reside.
__global__ void k_build_lin(const int* __restrict__ row, const int* __restrict__ col,
                            int* __restrict__ cur, int* __restrict__ deg,
                            int* __restrict__ bucket, int2* __restrict__ ovf,
                            int* __restrict__ ovf_cnt, int E, int nBuild, int nTotal,
                            const float* __restrict__ x, const float* __restrict__ W,
                            const float* __restrict__ b, ushort4* __restrict__ outb, int n) {
    int bid = blockIdx.x;
    int b_lo = (int)(((long long)bid * nBuild) / nTotal);
    int b_hi = (int)(((long long)(bid + 1) * nBuild) / nTotal);
    if (b_hi > b_lo) {
        // ---- build path ----
        int i = b_lo * TPB + threadIdx.x;
        if (i >= E) return;
        int r = row[i], c = col[i];
        atomicAdd(&deg[r], 1);
        int slot = atomicAdd(&cur[c], 1);
        if (slot < CAP) {
            __builtin_nontemporal_store(r, &bucket[c * CAP + slot]);
        } else {
            int p = atomicAdd(ovf_cnt, 1);
            if (p < OVF_CAP) ovf[p] = make_int2(r, c);
        }
        return;
    }
    // ---- lin128 path (split-K: Ws is 64x64) ----
    __shared__ float Ws[64][64];
    __shared__ float xs[16][132];
    int tid = threadIdx.x;
    int row0 = (bid - b_lo) * 16;
    for (int i = tid; i < 16 * 32; i += TPB) {
        int r = i >> 5, k4 = i & 31;
        int gr = row0 + r;
        float4 v = (gr < n) ? ((const float4*)(x + (size_t)gr * 128))[k4]
                            : make_float4(0.f, 0.f, 0.f, 0.f);
        ((float4*)&xs[r][0])[k4] = v;
    }
    int r = tid >> 4, c4 = (tid & 15) * 4;
    float4 acc = make_float4(b[c4], b[c4 + 1], b[c4 + 2], b[c4 + 3]);
#pragma unroll
    for (int half = 0; half < 2; ++half) {
        for (int i = tid; i < 64 * 64 / 4; i += TPB)
            ((float4*)&Ws[0][0])[i] = ((const float4*)W)[half * 1024 + i];
        __syncthreads();
#pragma unroll 8
        for (int k = 0; k < 64; ++k) {
            float xv = xs[r][half * 64 + k];
            float4 w = *(const float4*)&Ws[k][c4];
            acc.x += xv * w.x;
            acc.y += xv * w.y;
            acc.z += xv * w.z;
            acc.w += xv * w.w;
        }
        __syncthreads();
    }
    int gr = row0 + r;
    if (gr < n) outb[(size_t)gr * 16 + (tid & 15)] = f4b(acc);
}

// g0 = relu(hw[0]*hA + hw[1]*hB) @ W[64,64] + b   (bf16 in, bf16 out)
__global__ void k_lin64_relu2(const ushort4* __restrict__ hA, const ushort4* __restrict__ hB,
                              const float* __restrict__ W, const float* __restrict__ b,
                              const float* __restrict__ hw, ushort4* __restrict__ outb, int n) {
    __shared__ float Ws[64][64];
    __shared__ float xs[16][68];
    int tid = threadIdx.x;
    for (int i = tid; i < 64 * 64 / 4; i += TPB)
        ((float4*)&Ws[0][0])[i] = ((const float4*)W)[i];
    float w0 = hw[0], w1 = hw[1];
    int row0 = blockIdx.x * 16;
    for (int i = tid; i < 16 * 16; i += TPB) {
        int r = i >> 4, k4 = i & 15;
        int gr = row0 + r;
        float4 v = make_float4(0.f, 0.f, 0.f, 0.f);
        if (gr < n) {
            float4 a = b4f(hA[(size_t)gr * 16 + k4]);
            float4 c = b4f(hB[(size_t)gr * 16 + k4]);
            v.x = fmaxf(w0 * a.x + w1 * c.x, 0.f);
            v.y = fmaxf(w0 * a.y + w1 * c.y, 0.f);
            v.z = fmaxf(w0 * a.z + w1 * c.z, 0.f);
            v.w = fmaxf(w0 * a.w + w1 * c.w, 0.f);
        }
        ((float4*)&xs[r][0])[k4] = v;
    }
    __syncthreads();
    int r = tid >> 4, c4 = (tid & 15) * 4;
    float4 acc = make_float4(b[c4], b[c4 + 1], b[c4 + 2], b[c4 + 3]);
#pragma unroll 8
    for (int k = 0; k < 64; ++k) {
        float xv = xs[r][k];
        float4 w = *(const float4*)&Ws[k][c4];
        acc.x += xv * w.x;
        acc.y += xv * w.y;
        acc.z += xv * w.z;
        acc.w += xv * w.w;
    }
    int gr = row0 + r;
    if (gr < n) outb[(size_t)gr * 16 + (tid & 15)] = f4b(acc);
}

// Wave-per-node gather: 4 edge-groups x 16 channel-lanes (4 bf16 ch/lane).
// Norms on the fly: w(r) = rsqrt(deg[r]+1). Overflow handled inline.
//   agg = dc*(dc*h[c] + sum_e w(r)*h[r])
// mode 0: outb = bf16(agg);  mode 2: outf = hw[0]*h + hw[1]*agg  (f32)
__global__ void k_gather(const ushort4* __restrict__ h, ushort4* __restrict__ outb,
                         float4* __restrict__ outf,
                         const int* __restrict__ cur, const int* __restrict__ bucket,
                         const int* __restrict__ deg_, const float* __restrict__ hw,
                         const int2* __restrict__ ovf, const int* __restrict__ ovf_cnt,
                         int n, int mode) {
    int node = blockIdx.x * 4 + (threadIdx.x >> 6);
    if (node >= n) return;
    int lane = threadIdx.x & 63;
    int g = lane >> 4, cl = lane & 15;
    float dc = rsqrtf((float)deg_[node] + 1.0f);
    float4 hv = b4f(h[(size_t)node * 16 + cl]);
    float4 S = (g == 0) ? make_float4(dc * hv.x, dc * hv.y, dc * hv.z, dc * hv.w)
                        : make_float4(0.f, 0.f, 0.f, 0.f);
    int degFull = cur[node];
    int deg = min(degFull, CAP);
    const int4v* bp4 = (const int4v*)(bucket + node * CAP);  // 160 B stride
    for (int base = g * 4; base < deg; base += 16) {
        int4v e = __builtin_nontemporal_load(&bp4[base >> 2]);
        int r0 = (base + 0 < deg) ? e[0] : node;
        int r1 = (base + 1 < deg) ? e[1] : node;
        int r2 = (base + 2 < deg) ? e[2] : node;
        int r3 = (base + 3 < deg) ? e[3] : node;
        int d0 = deg_[r0], d1 = deg_[r1], d2 = deg_[r2], d3 = deg_[r3];
        float w0 = (base + 0 < deg) ? rsqrtf((float)d0 + 1.f) : 0.f;
        float w1 = (base + 1 < deg) ? rsqrtf((float)d1 + 1.f) : 0.f;
        float w2 = (base + 2 < deg) ? rsqrtf((float)d2 + 1.f) : 0.f;
        float w3 = (base + 3 < deg) ? rsqrtf((float)d3 + 1.f) : 0.f;
        float4 v0 = b4f(h[(size_t)r0 * 16 + cl]);
        float4 v1 = b4f(h[(size_t)r1 * 16 + cl]);
        float4 v2 = b4f(h[(size_t)r2 * 16 + cl]);
        float4 v3 = b4f(h[(size_t)r3 * 16 + cl]);
        S.x += w0 * v0.x + w1 * v1.x + w2 * v2.x + w3 * v3.x;
        S.y += w0 * v0.y + w1 * v1.y + w2 * v2.y + w3 * v3.y;
        S.z += w0 * v0.z + w1 * v1.z + w2 * v2.z + w3 * v3.z;
        S.w += w0 * v0.w + w1 * v1.w + w2 * v2.w + w3 * v3.w;
    }
    if (degFull > CAP) {  // overflow: scan spill list for edges into this node
        int m = min(*ovf_cnt, OVF_CAP);
        for (int i = g; i < m; i += 4) {
            int2 p = ovf[i];
            if (p.y == node) {
                float w = rsqrtf((float)deg_[p.x] + 1.f);
                float4 v = b4f(h[(size_t)p.x * 16 + cl]);
                S.x += w * v.x; S.y += w * v.y; S.z += w * v.z; S.w += w * v.w;
            }
        }
    }
    // reduce the 4 edge-groups (same cl): xor lanes 16, 32
    S.x += __shfl_xor(S.x, 16); S.y += __shfl_xor(S.y, 16);
    S.z += __shfl_xor(S.z, 16); S.w += __shfl_xor(S.w, 16);
    S.x += __shfl_xor(S.x, 32); S.y += __shfl_xor(S.y, 32);
    S.z += __shfl_xor(S.z, 32); S.w += __shfl_xor(S.w, 32);
    if (g != 0) return;
    float4 acc = make_float4(dc * S.x, dc * S.y, dc * S.z, dc * S.w);
    if (mode == 2) {
        float w0 = hw[0], w1 = hw[1];
        acc.x = w0 * hv.x + w1 * acc.x;
        acc.y = w0 * hv.y + w1 * acc.y;
        acc.z = w0 * hv.z + w1 * acc.z;
        acc.w = w0 * hv.w + w1 * acc.w;
        outf[(size_t)node * 16 + cl] = acc;
    } else {
        outb[(size_t)node * 16 + cl] = f4b(acc);
    }
}

// ---- launch --------------------------------------------------------------

static inline size_t align_up(size_t v, size_t a) { return (v + a - 1) & ~(a - 1); }

extern "C" void kernel_launch(void* const* d_in, const int* in_sizes, int n_in,
                              void* d_out, int out_size, void* d_ws, size_t ws_size,
                              hipStream_t stream) {
    const float* x   = (const float*)d_in[0];
    const int*   ei  = (const int*)d_in[1];
    const float* W1  = (const float*)d_in[2];
    const float* b1  = (const float*)d_in[3];
    const float* hw1 = (const float*)d_in[4];
    const float* W2  = (const float*)d_in[5];
    const float* b2  = (const float*)d_in[6];
    const float* hw2 = (const float*)d_in[7];
    float* out = (float*)d_out;

    const int E = in_sizes[1] / 2;
    const int n = out_size / 64;
    const int* row = ei;
    const int* col = ei + E;

    char* ws = (char*)d_ws;
    size_t o = 0;
    int*     cur    = (int*)(ws + o);     size_t z0 = o; o = align_up(o + (size_t)n * 4, 512);
    int*     deg    = (int*)(ws + o);     o = align_up(o + (size_t)n * 4, 512);
    int*     ovfcnt = (int*)(ws + o);     size_t z1 = o + 4; o = align_up(z1, 512);
    int*     bucket = (int*)(ws + o);     o = align_up(o + (size_t)n * CAP * 4, 512);
    int2*    ovf    = (int2*)(ws + o);    o = align_up(o + (size_t)OVF_CAP * 8, 512);
    ushort4* A      = (ushort4*)(ws + o); o = align_up(o + (size_t)n * 64 * 2, 512);
    ushort4* B      = (ushort4*)(ws + o); o = align_up(o + (size_t)n * 64 * 2, 512);
    ushort4* C      = (ushort4*)(ws + o); o = align_up(o + (size_t)n * 64 * 2, 512);
    (void)ws_size;

    const int nBuild = (E + TPB - 1) / TPB;
    const int nLin   = (n + 15) / 16;
    const int nTotal = nBuild + nLin;
    dim3 blk(TPB);
    dim3 gG((n + 3) / 4);      // 1 wave per node, 4 waves per block
    dim3 gLin(nLin);

    // zero cur/deg/ovf_cnt, then fused {build | lin128} (interleaved blocks)
    (void)hipMemsetAsync(ws + z0, 0, z1 - z0, stream);
    k_build_lin<<<dim3(nTotal), blk, 0, stream>>>(
        row, col, cur, deg, bucket, ovf, ovfcnt, E, nBuild, nTotal,
        x, W1, b1, A, n);                                                   // A = h0 (bf16)

    // ---- layer 1 ----  (combine+relu fused into k_lin64_relu2 staging)
    k_gather<<<gG, blk, 0, stream>>>(A, B, nullptr, cur, bucket, deg, hw1,
                                     ovf, ovfcnt, n, 0);                    // B = h1
    k_gather<<<gG, blk, 0, stream>>>(B, C, nullptr, cur, bucket, deg, hw1,
                                     ovf, ovfcnt, n, 0);                    // C = h2

    // ---- layer 2 ----
    k_lin64_relu2<<<gLin, blk, 0, stream>>>(B, C, W2, b2, hw1, A, n);       // A = g0
    k_gather<<<gG, blk, 0, stream>>>(A, B, nullptr, cur, bucket, deg, hw2,
                                     ovf, ovfcnt, n, 0);                    // B = g1
    k_gather<<<gG, blk, 0, stream>>>(B, nullptr, (float4*)out, cur, bucket, deg, hw2,
                                     ovf, ovfcnt, n, 2);                    // out = w0*g1+w1*agg
}

// Round 12
// 282.566 us; speedup vs baseline: 1.0671x; 1.0671x over previous
//
#include <hip/hip_runtime.h>

// MultiHopGCN: x[N,128] f32, edge_index[2,E] i32, W1[128,64], b1[64], hw1[2],
//              W2[64,64], b2[64], hw2[2] -> out[N,64] f32
// Bucketed-CSC build fused with layer-1 GEMM; wave-per-node gather.
// bf16 intermediate features; nontemporal bucket STORES only (build-side:
// avoids write-allocate ping-pong; gather re-reads stay L2-cached).

#define TPB 256
#define CAP 40
#define OVF_CAP 65536

// bf16 helpers (RNE)
__device__ __forceinline__ ushort f2b(float f) {
    union { float f; unsigned u; } v; v.f = f;
    unsigned r = v.u + 0x7FFFu + ((v.u >> 16) & 1u);
    return (ushort)(r >> 16);
}
__device__ __forceinline__ float b2f(ushort b) {
    union { unsigned u; float f; } v; v.u = ((unsigned)b) << 16;
    return v.f;
}
__device__ __forceinline__ float4 b4f(ushort4 b) {
    return make_float4(b2f(b.x), b2f(b.y), b2f(b.z), b2f(b.w));
}
__device__ __forceinline__ ushort4 f4b(float4 f) {
    ushort4 r; r.x = f2b(f.x); r.y = f2b(f.y); r.z = f2b(f.z); r.w = f2b(f.w);
    return r;
}

// ---- fused build + lin128 -------------------------------------------------
// Build blocks and GEMM blocks Bresenham-interleaved so both kinds co-reside.
__global__ void k_build_lin(const int* __restrict__ row, const int* __restrict__ col,
                            int* __restrict__ cur, int* __restrict__ deg,
                            int* __restrict__ bucket, int2* __restrict__ ovf,
                            int* __restrict__ ovf_cnt, int E, int nBuild, int nTotal,
                            const float* __restrict__ x, const float* __restrict__ W,
                            const float* __restrict__ b, ushort4* __restrict__ outb, int n) {
    int bid = blockIdx.x;
    int b_lo = (int)(((long long)bid * nBuild) / nTotal);
    int b_hi = (int)(((long long)(bid + 1) * nBuild) / nTotal);
    if (b_hi > b_lo) {
        // ---- build path ----
        int i = b_lo * TPB + threadIdx.x;
        if (i >= E) return;
        int r = row[i], c = col[i];
        atomicAdd(&deg[r], 1);
        int slot = atomicAdd(&cur[c], 1);
        if (slot < CAP) {
            __builtin_nontemporal_store(r, &bucket[c * CAP + slot]);
        } else {
            int p = atomicAdd(ovf_cnt, 1);
            if (p < OVF_CAP) ovf[p] = make_int2(r, c);
        }
        return;
    }
    // ---- lin128 path (split-K: Ws is 64x64) ----
    __shared__ float Ws[64][64];
    __shared__ float xs[16][132];
    int tid = threadIdx.x;
    int row0 = (bid - b_lo) * 16;
    for (int i = tid; i < 16 * 32; i += TPB) {
        int r = i >> 5, k4 = i & 31;
        int gr = row0 + r;
        float4 v = (gr < n) ? ((const float4*)(x + (size_t)gr * 128))[k4]
                            : make_float4(0.f, 0.f, 0.f, 0.f);
        ((float4*)&xs[r][0])[k4] = v;
    }
    int r = tid >> 4, c4 = (tid & 15) * 4;
    float4 acc = make_float4(b[c4], b[c4 + 1], b[c4 + 2], b[c4 + 3]);
#pragma unroll
    for (int half = 0; half < 2; ++half) {
        for (int i = tid; i < 64 * 64 / 4; i += TPB)
            ((float4*)&Ws[0][0])[i] = ((const float4*)W)[half * 1024 + i];
        __syncthreads();
#pragma unroll 8
        for (int k = 0; k < 64; ++k) {
            float xv = xs[r][half * 64 + k];
            float4 w = *(const float4*)&Ws[k][c4];
            acc.x += xv * w.x;
            acc.y += xv * w.y;
            acc.z += xv * w.z;
            acc.w += xv * w.w;
        }
        __syncthreads();
    }
    int gr = row0 + r;
    if (gr < n) outb[(size_t)gr * 16 + (tid & 15)] = f4b(acc);
}

// g0 = relu(hw[0]*hA + hw[1]*hB) @ W[64,64] + b   (bf16 in, bf16 out)
__global__ void k_lin64_relu2(const ushort4* __restrict__ hA, const ushort4* __restrict__ hB,
                              const float* __restrict__ W, const float* __restrict__ b,
                              const float* __restrict__ hw, ushort4* __restrict__ outb, int n) {
    __shared__ float Ws[64][64];
    __shared__ float xs[16][68];
    int tid = threadIdx.x;
    for (int i = tid; i < 64 * 64 / 4; i += TPB)
        ((float4*)&Ws[0][0])[i] = ((const float4*)W)[i];
    float w0 = hw[0], w1 = hw[1];
    int row0 = blockIdx.x * 16;
    for (int i = tid; i < 16 * 16; i += TPB) {
        int r = i >> 4, k4 = i & 15;
        int gr = row0 + r;
        float4 v = make_float4(0.f, 0.f, 0.f, 0.f);
        if (gr < n) {
            float4 a = b4f(hA[(size_t)gr * 16 + k4]);
            float4 c = b4f(hB[(size_t)gr * 16 + k4]);
            v.x = fmaxf(w0 * a.x + w1 * c.x, 0.f);
            v.y = fmaxf(w0 * a.y + w1 * c.y, 0.f);
            v.z = fmaxf(w0 * a.z + w1 * c.z, 0.f);
            v.w = fmaxf(w0 * a.w + w1 * c.w, 0.f);
        }
        ((float4*)&xs[r][0])[k4] = v;
    }
    __syncthreads();
    int r = tid >> 4, c4 = (tid & 15) * 4;
    float4 acc = make_float4(b[c4], b[c4 + 1], b[c4 + 2], b[c4 + 3]);
#pragma unroll 8
    for (int k = 0; k < 64; ++k) {
        float xv = xs[r][k];
        float4 w = *(const float4*)&Ws[k][c4];
        acc.x += xv * w.x;
        acc.y += xv * w.y;
        acc.z += xv * w.z;
        acc.w += xv * w.w;
    }
    int gr = row0 + r;
    if (gr < n) outb[(size_t)gr * 16 + (tid & 15)] = f4b(acc);
}

// Wave-per-node gather: 4 edge-groups x 16 channel-lanes (4 bf16 ch/lane).
// Norms on the fly: w(r) = rsqrt(deg[r]+1). Overflow handled inline.
//   agg = dc*(dc*h[c] + sum_e w(r)*h[r])
// mode 0: outb = bf16(agg);  mode 2: outf = hw[0]*h + hw[1]*agg  (f32)
__global__ void k_gather(const ushort4* __restrict__ h, ushort4* __restrict__ outb,
                         float4* __restrict__ outf,
                         const int* __restrict__ cur, const int* __restrict__ bucket,
                         const int* __restrict__ deg_, const float* __restrict__ hw,
                         const int2* __restrict__ ovf, const int* __restrict__ ovf_cnt,
                         int n, int mode) {
    int node = blockIdx.x * 4 + (threadIdx.x >> 6);
    if (node >= n) return;
    int lane = threadIdx.x & 63;
    int g = lane >> 4, cl = lane & 15;
    float dc = rsqrtf((float)deg_[node] + 1.0f);
    float4 hv = b4f(h[(size_t)node * 16 + cl]);
    float4 S = (g == 0) ? make_float4(dc * hv.x, dc * hv.y, dc * hv.z, dc * hv.w)
                        : make_float4(0.f, 0.f, 0.f, 0.f);
    int degFull = cur[node];
    int deg = min(degFull, CAP);
    const int4* bp4 = (const int4*)(bucket + node * CAP);  // 160 B stride
    for (int base = g * 4; base < deg; base += 16) {
        int4 e = bp4[base >> 2];
        int r0 = (base + 0 < deg) ? e.x : node;
        int r1 = (base + 1 < deg) ? e.y : node;
        int r2 = (base + 2 < deg) ? e.z : node;
        int r3 = (base + 3 < deg) ? e.w : node;
        int d0 = deg_[r0], d1 = deg_[r1], d2 = deg_[r2], d3 = deg_[r3];
        float w0 = (base + 0 < deg) ? rsqrtf((float)d0 + 1.f) : 0.f;
        float w1 = (base + 1 < deg) ? rsqrtf((float)d1 + 1.f) : 0.f;
        float w2 = (base + 2 < deg) ? rsqrtf((float)d2 + 1.f) : 0.f;
        float w3 = (base + 3 < deg) ? rsqrtf((float)d3 + 1.f) : 0.f;
        float4 v0 = b4f(h[(size_t)r0 * 16 + cl]);
        float4 v1 = b4f(h[(size_t)r1 * 16 + cl]);
        float4 v2 = b4f(h[(size_t)r2 * 16 + cl]);
        float4 v3 = b4f(h[(size_t)r3 * 16 + cl]);
        S.x += w0 * v0.x + w1 * v1.x + w2 * v2.x + w3 * v3.x;
        S.y += w0 * v0.y + w1 * v1.y + w2 * v2.y + w3 * v3.y;
        S.z += w0 * v0.z + w1 * v1.z + w2 * v2.z + w3 * v3.z;
        S.w += w0 * v0.w + w1 * v1.w + w2 * v2.w + w3 * v3.w;
    }
    if (degFull > CAP) {  // overflow: scan spill list for edges into this node
        int m = min(*ovf_cnt, OVF_CAP);
        for (int i = g; i < m; i += 4) {
            int2 p = ovf[i];
            if (p.y == node) {
                float w = rsqrtf((float)deg_[p.x] + 1.f);
                float4 v = b4f(h[(size_t)p.x * 16 + cl]);
                S.x += w * v.x; S.y += w * v.y; S.z += w * v.z; S.w += w * v.w;
            }
        }
    }
    // reduce the 4 edge-groups (same cl): xor lanes 16, 32
    S.x += __shfl_xor(S.x, 16); S.y += __shfl_xor(S.y, 16);
    S.z += __shfl_xor(S.z, 16); S.w += __shfl_xor(S.w, 16);
    S.x += __shfl_xor(S.x, 32); S.y += __shfl_xor(S.y, 32);
    S.z += __shfl_xor(S.z, 32); S.w += __shfl_xor(S.w, 32);
    if (g != 0) return;
    float4 acc = make_float4(dc * S.x, dc * S.y, dc * S.z, dc * S.w);
    if (mode == 2) {
        float w0 = hw[0], w1 = hw[1];
        acc.x = w0 * hv.x + w1 * acc.x;
        acc.y = w0 * hv.y + w1 * acc.y;
        acc.z = w0 * hv.z + w1 * acc.z;
        acc.w = w0 * hv.w + w1 * acc.w;
        outf[(size_t)node * 16 + cl] = acc;
    } else {
        outb[(size_t)node * 16 + cl] = f4b(acc);
    }
}

// ---- launch --------------------------------------------------------------

static inline size_t align_up(size_t v, size_t a) { return (v + a - 1) & ~(a - 1); }

extern "C" void kernel_launch(void* const* d_in, const int* in_sizes, int n_in,
                              void* d_out, int out_size, void* d_ws, size_t ws_size,
                              hipStream_t stream) {
    const float* x   = (const float*)d_in[0];
    const int*   ei  = (const int*)d_in[1];
    const float* W1  = (const float*)d_in[2];
    const float* b1  = (const float*)d_in[3];
    const float* hw1 = (const float*)d_in[4];
    const float* W2  = (const float*)d_in[5];
    const float* b2  = (const float*)d_in[6];
    const float* hw2 = (const float*)d_in[7];
    float* out = (float*)d_out;

    const int E = in_sizes[1] / 2;
    const int n = out_size / 64;
    const int* row = ei;
    const int* col = ei + E;

    char* ws = (char*)d_ws;
    size_t o = 0;
    int*     cur    = (int*)(ws + o);     size_t z0 = o; o = align_up(o + (size_t)n * 4, 512);
    int*     deg    = (int*)(ws + o);     o = align_up(o + (size_t)n * 4, 512);
    int*     ovfcnt = (int*)(ws + o);     size_t z1 = o + 4; o = align_up(z1, 512);
    int*     bucket = (int*)(ws + o);     o = align_up(o + (size_t)n * CAP * 4, 512);
    int2*    ovf    = (int2*)(ws + o);    o = align_up(o + (size_t)OVF_CAP * 8, 512);
    ushort4* A      = (ushort4*)(ws + o); o = align_up(o + (size_t)n * 64 * 2, 512);
    ushort4* B      = (ushort4*)(ws + o); o = align_up(o + (size_t)n * 64 * 2, 512);
    ushort4* C      = (ushort4*)(ws + o); o = align_up(o + (size_t)n * 64 * 2, 512);
    (void)ws_size;

    const int nBuild = (E + TPB - 1) / TPB;
    const int nLin   = (n + 15) / 16;
    const int nTotal = nBuild + nLin;
    dim3 blk(TPB);
    dim3 gG((n + 3) / 4);      // 1 wave per node, 4 waves per block
    dim3 gLin(nLin);

    // zero cur/deg/ovf_cnt, then fused {build | lin128} (interleaved blocks)
    (void)hipMemsetAsync(ws + z0, 0, z1 - z0, stream);
    k_build_lin<<<dim3(nTotal), blk, 0, stream>>>(
        row, col, cur, deg, bucket, ovf, ovfcnt, E, nBuild, nTotal,
        x, W1, b1, A, n);                                                   // A = h0 (bf16)

    // ---- layer 1 ----  (combine+relu fused into k_lin64_relu2 staging)
    k_gather<<<gG, blk, 0, stream>>>(A, B, nullptr, cur, bucket, deg, hw1,
                                     ovf, ovfcnt, n, 0);                    // B = h1
    k_gather<<<gG, blk, 0, stream>>>(B, C, nullptr, cur, bucket, deg, hw1,
                                     ovf, ovfcnt, n, 0);                    // C = h2

    // ---- layer 2 ----
    k_lin64_relu2<<<gLin, blk, 0, stream>>>(B, C, W2, b2, hw1, A, n);       // A = g0
    k_gather<<<gG, blk, 0, stream>>>(A, B, nullptr, cur, bucket, deg, hw2,
                                     ovf, ovfcnt, n, 0);                    // B = g1
    k_gather<<<gG, blk, 0, stream>>>(B, nullptr, (float4*)out, cur, bucket, deg, hw2,
                                     ovf, ovfcnt, n, 2);                    // out = w0*g1+w1*agg
}

// Round 13
// 265.593 us; speedup vs baseline: 1.1353x; 1.0639x over previous
//
#include <hip/hip_runtime.h>

// MultiHopGCN: x[N,128] f32, edge_index[2,E] i32, W1[128,64], b1[64], hw1[2],
//              W2[64,64], b2[64], hw2[2] -> out[N,64] f32
// Bucketed-CSC build fused with layer-1 GEMM. Features stored PRE-SCALED
// (s = dis*h, bf16): every hop becomes a weight-free sum of gathered rows
//   s'_c = dc^2 * (s_c + sum_r s_r)
// so the gather inner loop has NO per-edge deg/rsqrt/weight work.

#define TPB 256
#define CAP 40
#define OVF_CAP 65536

// bf16 helpers (RNE)
__device__ __forceinline__ ushort f2b(float f) {
    union { float f; unsigned u; } v; v.f = f;
    unsigned r = v.u + 0x7FFFu + ((v.u >> 16) & 1u);
    return (ushort)(r >> 16);
}
__device__ __forceinline__ float b2f(ushort b) {
    union { unsigned u; float f; } v; v.u = ((unsigned)b) << 16;
    return v.f;
}
__device__ __forceinline__ float4 b4f(ushort4 b) {
    return make_float4(b2f(b.x), b2f(b.y), b2f(b.z), b2f(b.w));
}
__device__ __forceinline__ ushort4 f4b(float4 f) {
    ushort4 r; r.x = f2b(f.x); r.y = f2b(f.y); r.z = f2b(f.z); r.w = f2b(f.w);
    return r;
}

// ---- fused build + lin128 -------------------------------------------------
__global__ void k_build_lin(const int* __restrict__ row, const int* __restrict__ col,
                            int* __restrict__ cur, int* __restrict__ deg,
                            int* __restrict__ bucket, int2* __restrict__ ovf,
                            int* __restrict__ ovf_cnt, int E, int nBuild, int nTotal,
                            const float* __restrict__ x, const float* __restrict__ W,
                            const float* __restrict__ b, ushort4* __restrict__ outb, int n) {
    int bid = blockIdx.x;
    int b_lo = (int)(((long long)bid * nBuild) / nTotal);
    int b_hi = (int)(((long long)(bid + 1) * nBuild) / nTotal);
    if (b_hi > b_lo) {
        // ---- build path ----
        int i = b_lo * TPB + threadIdx.x;
        if (i >= E) return;
        int r = row[i], c = col[i];
        atomicAdd(&deg[r], 1);
        int slot = atomicAdd(&cur[c], 1);
        if (slot < CAP) {
            __builtin_nontemporal_store(r, &bucket[c * CAP + slot]);
        } else {
            int p = atomicAdd(ovf_cnt, 1);
            if (p < OVF_CAP) ovf[p] = make_int2(r, c);
        }
        return;
    }
    // ---- lin128 path (split-K: Ws is 64x64) ----
    __shared__ float Ws[64][64];
    __shared__ float xs[16][132];
    int tid = threadIdx.x;
    int row0 = (bid - b_lo) * 16;
    for (int i = tid; i < 16 * 32; i += TPB) {
        int r = i >> 5, k4 = i & 31;
        int gr = row0 + r;
        float4 v = (gr < n) ? ((const float4*)(x + (size_t)gr * 128))[k4]
                            : make_float4(0.f, 0.f, 0.f, 0.f);
        ((float4*)&xs[r][0])[k4] = v;
    }
    int r = tid >> 4, c4 = (tid & 15) * 4;
    float4 acc = make_float4(b[c4], b[c4 + 1], b[c4 + 2], b[c4 + 3]);
#pragma unroll
    for (int half = 0; half < 2; ++half) {
        for (int i = tid; i < 64 * 64 / 4; i += TPB)
            ((float4*)&Ws[0][0])[i] = ((const float4*)W)[half * 1024 + i];
        __syncthreads();
#pragma unroll 8
        for (int k = 0; k < 64; ++k) {
            float xv = xs[r][half * 64 + k];
            float4 w = *(const float4*)&Ws[k][c4];
            acc.x += xv * w.x;
            acc.y += xv * w.y;
            acc.z += xv * w.z;
            acc.w += xv * w.w;
        }
        __syncthreads();
    }
    int gr = row0 + r;
    if (gr < n) outb[(size_t)gr * 16 + (tid & 15)] = f4b(acc);
}

// in-place pre-scale: A[node] *= rsqrt(deg[node]+1)
__global__ void k_scale(ushort4* __restrict__ A, const int* __restrict__ deg, int cnt16) {
    int i = blockIdx.x * blockDim.x + threadIdx.x;
    if (i >= cnt16) return;
    int node = i >> 4;
    float dc = rsqrtf((float)deg[node] + 1.0f);
    float4 v = b4f(A[i]);
    A[i] = f4b(make_float4(dc * v.x, dc * v.y, dc * v.z, dc * v.w));
}

// g0s = dis * ( relu(hw[0]*inv*s1 + hw[1]*inv*s2) @ W + b )   (bf16 scaled I/O)
__global__ void k_lin64_relu2(const ushort4* __restrict__ s1, const ushort4* __restrict__ s2,
                              const float* __restrict__ W, const float* __restrict__ b,
                              const float* __restrict__ hw, const int* __restrict__ deg,
                              ushort4* __restrict__ outb, int n) {
    __shared__ float Ws[64][64];
    __shared__ float xs[16][68];
    int tid = threadIdx.x;
    for (int i = tid; i < 64 * 64 / 4; i += TPB)
        ((float4*)&Ws[0][0])[i] = ((const float4*)W)[i];
    float w0 = hw[0], w1 = hw[1];
    int row0 = blockIdx.x * 16;
    for (int i = tid; i < 16 * 16; i += TPB) {
        int r = i >> 4, k4 = i & 15;
        int gr = row0 + r;
        float4 v = make_float4(0.f, 0.f, 0.f, 0.f);
        if (gr < n) {
            float inv = sqrtf((float)deg[gr] + 1.0f);  // 1/dc: unscale
            float4 a = b4f(s1[(size_t)gr * 16 + k4]);
            float4 c = b4f(s2[(size_t)gr * 16 + k4]);
            v.x = fmaxf(inv * (w0 * a.x + w1 * c.x), 0.f);
            v.y = fmaxf(inv * (w0 * a.y + w1 * c.y), 0.f);
            v.z = fmaxf(inv * (w0 * a.z + w1 * c.z), 0.f);
            v.w = fmaxf(inv * (w0 * a.w + w1 * c.w), 0.f);
        }
        ((float4*)&xs[r][0])[k4] = v;
    }
    __syncthreads();
    int r = tid >> 4, c4 = (tid & 15) * 4;
    float4 acc = make_float4(b[c4], b[c4 + 1], b[c4 + 2], b[c4 + 3]);
#pragma unroll 8
    for (int k = 0; k < 64; ++k) {
        float xv = xs[r][k];
        float4 w = *(const float4*)&Ws[k][c4];
        acc.x += xv * w.x;
        acc.y += xv * w.y;
        acc.z += xv * w.z;
        acc.w += xv * w.w;
    }
    int gr = row0 + r;
    if (gr < n) {
        float dc = rsqrtf((float)deg[gr] + 1.0f);  // re-scale output
        outb[(size_t)gr * 16 + (tid & 15)] =
            f4b(make_float4(dc * acc.x, dc * acc.y, dc * acc.z, dc * acc.w));
    }
}

// Weight-free wave-per-node gather on pre-scaled features.
//   S = s_c + sum_r s_r   (bucket rows; 0/1 tail masks)
// mode 0: outb = bf16(dc^2 * S)
// mode 2: outf = hw[0]*inv*s_c + hw[1]*dc*S   (f32 final)
__global__ void k_gather(const ushort4* __restrict__ h, ushort4* __restrict__ outb,
                         float4* __restrict__ outf,
                         const int* __restrict__ cur, const int* __restrict__ bucket,
                         const int* __restrict__ deg_, const float* __restrict__ hw,
                         const int2* __restrict__ ovf, const int* __restrict__ ovf_cnt,
                         int n, int mode) {
    int node = blockIdx.x * 4 + (threadIdx.x >> 6);
    if (node >= n) return;
    int lane = threadIdx.x & 63;
    int g = lane >> 4, cl = lane & 15;
    float4 hv = b4f(h[(size_t)node * 16 + cl]);  // s_c
    float4 S = (g == 0) ? hv : make_float4(0.f, 0.f, 0.f, 0.f);
    int degFull = cur[node];
    int deg = min(degFull, CAP);
    const int4* bp4 = (const int4*)(bucket + node * CAP);  // 160 B stride
    for (int base = g * 4; base < deg; base += 16) {
        int4 e = bp4[base >> 2];
        int r0 = (base + 0 < deg) ? e.x : node;
        int r1 = (base + 1 < deg) ? e.y : node;
        int r2 = (base + 2 < deg) ? e.z : node;
        int r3 = (base + 3 < deg) ? e.w : node;
        float w0 = (base + 0 < deg) ? 1.f : 0.f;
        float w1 = (base + 1 < deg) ? 1.f : 0.f;
        float w2 = (base + 2 < deg) ? 1.f : 0.f;
        float w3 = (base + 3 < deg) ? 1.f : 0.f;
        float4 v0 = b4f(h[(size_t)r0 * 16 + cl]);
        float4 v1 = b4f(h[(size_t)r1 * 16 + cl]);
        float4 v2 = b4f(h[(size_t)r2 * 16 + cl]);
        float4 v3 = b4f(h[(size_t)r3 * 16 + cl]);
        S.x += w0 * v0.x + w1 * v1.x + w2 * v2.x + w3 * v3.x;
        S.y += w0 * v0.y + w1 * v1.y + w2 * v2.y + w3 * v3.y;
        S.z += w0 * v0.z + w1 * v1.z + w2 * v2.z + w3 * v3.z;
        S.w += w0 * v0.w + w1 * v1.w + w2 * v2.w + w3 * v3.w;
    }
    if (degFull > CAP) {  // overflow: scan spill list for edges into this node
        int m = min(*ovf_cnt, OVF_CAP);
        for (int i = g; i < m; i += 4) {
            int2 p = ovf[i];
            if (p.y == node) {
                float4 v = b4f(h[(size_t)p.x * 16 + cl]);
                S.x += v.x; S.y += v.y; S.z += v.z; S.w += v.w;
            }
        }
    }
    // reduce the 4 edge-groups (same cl): xor lanes 16, 32
    S.x += __shfl_xor(S.x, 16); S.y += __shfl_xor(S.y, 16);
    S.z += __shfl_xor(S.z, 16); S.w += __shfl_xor(S.w, 16);
    S.x += __shfl_xor(S.x, 32); S.y += __shfl_xor(S.y, 32);
    S.z += __shfl_xor(S.z, 32); S.w += __shfl_xor(S.w, 32);
    if (g != 0) return;
    float dc = rsqrtf((float)deg_[node] + 1.0f);
    if (mode == 2) {
        float inv = sqrtf((float)deg_[node] + 1.0f);
        float a0 = hw[0] * inv, a1 = hw[1] * dc;
        outf[(size_t)node * 16 + cl] = make_float4(
            a0 * hv.x + a1 * S.x, a0 * hv.y + a1 * S.y,
            a0 * hv.z + a1 * S.z, a0 * hv.w + a1 * S.w);
    } else {
        float d2 = dc * dc;
        outb[(size_t)node * 16 + cl] =
            f4b(make_float4(d2 * S.x, d2 * S.y, d2 * S.z, d2 * S.w));
    }
}

// ---- launch --------------------------------------------------------------

static inline size_t align_up(size_t v, size_t a) { return (v + a - 1) & ~(a - 1); }

extern "C" void kernel_launch(void* const* d_in, const int* in_sizes, int n_in,
                              void* d_out, int out_size, void* d_ws, size_t ws_size,
                              hipStream_t stream) {
    const float* x   = (const float*)d_in[0];
    const int*   ei  = (const int*)d_in[1];
    const float* W1  = (const float*)d_in[2];
    const float* b1  = (const float*)d_in[3];
    const float* hw1 = (const float*)d_in[4];
    const float* W2  = (const float*)d_in[5];
    const float* b2  = (const float*)d_in[6];
    const float* hw2 = (const float*)d_in[7];
    float* out = (float*)d_out;

    const int E = in_sizes[1] / 2;
    const int n = out_size / 64;
    const int* row = ei;
    const int* col = ei + E;

    char* ws = (char*)d_ws;
    size_t o = 0;
    int*     cur    = (int*)(ws + o);     size_t z0 = o; o = align_up(o + (size_t)n * 4, 512);
    int*     deg    = (int*)(ws + o);     o = align_up(o + (size_t)n * 4, 512);
    int*     ovfcnt = (int*)(ws + o);     size_t z1 = o + 4; o = align_up(z1, 512);
    int*     bucket = (int*)(ws + o);     o = align_up(o + (size_t)n * CAP * 4, 512);
    int2*    ovf    = (int2*)(ws + o);    o = align_up(o + (size_t)OVF_CAP * 8, 512);
    ushort4* A      = (ushort4*)(ws + o); o = align_up(o + (size_t)n * 64 * 2, 512);
    ushort4* B      = (ushort4*)(ws + o); o = align_up(o + (size_t)n * 64 * 2, 512);
    ushort4* C      = (ushort4*)(ws + o); o = align_up(o + (size_t)n * 64 * 2, 512);
    (void)ws_size;

    const int nBuild = (E + TPB - 1) / TPB;
    const int nLin   = (n + 15) / 16;
    const int nTotal = nBuild + nLin;
    const int cnt16  = n * 16;
    dim3 blk(TPB);
    dim3 gG((n + 3) / 4);      // 1 wave per node, 4 waves per block
    dim3 gS((cnt16 + TPB - 1) / TPB);
    dim3 gLin(nLin);

    // zero cur/deg/ovf_cnt, then fused {build | lin128} (interleaved blocks)
    (void)hipMemsetAsync(ws + z0, 0, z1 - z0, stream);
    k_build_lin<<<dim3(nTotal), blk, 0, stream>>>(
        row, col, cur, deg, bucket, ovf, ovfcnt, E, nBuild, nTotal,
        x, W1, b1, A, n);                                                   // A = h0 (bf16)
    k_scale<<<gS, blk, 0, stream>>>(A, deg, cnt16);                         // A = dis*h0

    // ---- layer 1 ----  (combine+relu fused into k_lin64_relu2 staging)
    k_gather<<<gG, blk, 0, stream>>>(A, B, nullptr, cur, bucket, deg, hw1,
                                     ovf, ovfcnt, n, 0);                    // B = dis*h1
    k_gather<<<gG, blk, 0, stream>>>(B, C, nullptr, cur, bucket, deg, hw1,
                                     ovf, ovfcnt, n, 0);                    // C = dis*h2

    // ---- layer 2 ----
    k_lin64_relu2<<<gLin, blk, 0, stream>>>(B, C, W2, b2, hw1, deg, A, n);  // A = dis*g0
    k_gather<<<gG, blk, 0, stream>>>(A, B, nullptr, cur, bucket, deg, hw2,
                                     ovf, ovfcnt, n, 0);                    // B = dis*g1
    k_gather<<<gG, blk, 0, stream>>>(B, nullptr, (float4*)out, cur, bucket, deg, hw2,
                                     ovf, ovfcnt, n, 2);                    // out f32
}